// Round 3
// baseline (612.788 us; speedup 1.0000x reference)
//
#include <hip/hip_runtime.h>
#include <math.h>

// sources: [4][32][512][512] fp32, kernels: [12][3][3] fp32, out: same shape as sources
#define NCH  4
#define NIMG 32
#define HH   512
#define WW   512

// Tile 64 wide x 16 high; halo 1 each side. All 4 channels in one block.
#define TW   64
#define TH   16
#define HTWU 66            // used halo width
#define HTW  68            // row stride in floats (272 B, 16B-aligned)
#define HTH  18
#define NPIX (HTH * HTWU)  // 1188 staged pixels per channel

#if __has_builtin(__builtin_amdgcn_exp2f)
#define EXP2(x) __builtin_amdgcn_exp2f(x)
#else
#define EXP2(x) exp2f(x)
#endif
#if __has_builtin(__builtin_amdgcn_logf)
#define LOG2(x) __builtin_amdgcn_logf(x)
#else
#define LOG2(x) __log2f(x)
#endif

// Load a 6-wide window row from a 16B-aligned LDS row pointer: b128 + b64.
__device__ __forceinline__ void load_row6(const float* __restrict__ row, float w[6]) {
    const float4 a = *(const float4*)row;
    const float2 b = *(const float2*)(row + 4);
    w[0] = a.x; w[1] = a.y; w[2] = a.z; w[3] = a.w; w[4] = b.x; w[5] = b.y;
}

// One directed pair (i <- j):
//   bleed_i += conv(A_j^3, kc) + conv(A_j * A_i^2, ki)
// Element-major: each window element's s^3 / t computed once, consumed immediately.
__device__ __forceinline__ void do_pair(
    const float Ai[3][6],
    const float (*Aj_tile)[HTW], int ty, int tx4,
    const float* __restrict__ ker, int kcIdx, int kiIdx,
    float acc[4])
{
    float Aj[3][6];
    #pragma unroll
    for (int r = 0; r < 3; ++r)
        load_row6(&Aj_tile[ty + r][tx4], Aj[r]);

    float kc[9], ki9[9];
    #pragma unroll
    for (int q = 0; q < 9; ++q) {
        kc[q]  = ker[kcIdx * 9 + q];   // block-uniform -> scalar loads
        ki9[q] = ker[kiIdx * 9 + q];
    }

    #pragma unroll
    for (int r = 0; r < 3; ++r) {
        #pragma unroll
        for (int q = 0; q < 6; ++q) {
            const float a  = Aj[r][q];
            const float ai = Ai[r][q];
            const float s3 = a * a * a;        // raw neighbor value
            const float t  = a * (ai * ai);    // inter_term value
            #pragma unroll
            for (int dx = 0; dx < 3; ++dx) {
                const int p = q - dx;
                if (p >= 0 && p < 4) {
                    acc[p] = fmaf(s3, kc[r * 3 + dx], acc[p]);
                    acc[p] = fmaf(t,  ki9[r * 3 + dx], acc[p]);
                }
            }
        }
    }
}

__global__ __launch_bounds__(256, 6) void bleed_kernel(
    const float* __restrict__ src,   // [4][32][512][512]
    const float* __restrict__ ker,   // [12][3][3]
    float* __restrict__ out)
{
    // Single LDS array: A = src^(1/3). raw = A^3, inter = A_j * A_i^2 (muls only).
    __shared__ __align__(16) float sA[NCH][HTH][HTW];   // 19584 B

    const int tid    = threadIdx.x;
    const int tx     = tid & 15;      // col group: cols 4*tx .. 4*tx+3
    const int ty     = tid >> 4;      // output row 0..15
    const int tx4    = tx * 4;
    const int tile_x = blockIdx.x * TW;
    const int tile_y = blockIdx.y * TH;
    const int n      = blockIdx.z;    // image index

    const size_t plane = (size_t)HH * WW;

    // ---- stage A = cbrt(src) for all 4 channels, zero-padded halo ----
    #pragma unroll
    for (int c = 0; c < NCH; ++c) {
        const float* sp = src + ((size_t)c * NIMG + n) * plane;
        for (int idx = tid; idx < NPIX; idx += 256) {
            const int ly  = idx / HTWU;
            const int lxx = idx - ly * HTWU;
            const int gy  = tile_y - 1 + ly;
            const int gx  = tile_x - 1 + lxx;
            float v = 0.0f;
            if ((unsigned)gy < HH && (unsigned)gx < WW)
                v = sp[(size_t)gy * WW + gx];
            // v==0 -> log2 = -inf -> exp2 = 0 (correct). v in [0,1).
            sA[c][ly][lxx] = EXP2(0.33333333f * LOG2(v));
        }
    }
    __syncthreads();   // only barrier; everything after is read-only LDS

    const int gy  = tile_y + ty;
    const int gx0 = tile_x + tx4;

    float Ai[3][6];
    float acc[4];

    // ---- channel 0: bleed from j=1 (k0,k1) ----
    #pragma unroll
    for (int r = 0; r < 3; ++r) load_row6(&sA[0][ty + r][tx4], Ai[r]);
    acc[0] = acc[1] = acc[2] = acc[3] = 0.f;
    do_pair(Ai, sA[1], ty, tx4, ker, 0, 1, acc);
    {
        float4 o;
        float c0 = Ai[1][1], c1 = Ai[1][2], c2 = Ai[1][3], c3 = Ai[1][4];
        o.x = c0 * c0 * c0 - acc[0];
        o.y = c1 * c1 * c1 - acc[1];
        o.z = c2 * c2 * c2 - acc[2];
        o.w = c3 * c3 * c3 - acc[3];
        *(float4*)(out + ((size_t)0 * NIMG + n) * plane + (size_t)gy * WW + gx0) = o;
    }

    // ---- channel 1: bleed from j=0 (k2,k3) and j=2 (k4,k5) ----
    #pragma unroll
    for (int r = 0; r < 3; ++r) load_row6(&sA[1][ty + r][tx4], Ai[r]);
    acc[0] = acc[1] = acc[2] = acc[3] = 0.f;
    do_pair(Ai, sA[0], ty, tx4, ker, 2, 3, acc);
    do_pair(Ai, sA[2], ty, tx4, ker, 4, 5, acc);
    {
        float4 o;
        float c0 = Ai[1][1], c1 = Ai[1][2], c2 = Ai[1][3], c3 = Ai[1][4];
        o.x = c0 * c0 * c0 - acc[0];
        o.y = c1 * c1 * c1 - acc[1];
        o.z = c2 * c2 * c2 - acc[2];
        o.w = c3 * c3 * c3 - acc[3];
        *(float4*)(out + ((size_t)1 * NIMG + n) * plane + (size_t)gy * WW + gx0) = o;
    }

    // ---- channel 2: bleed from j=1 (k6,k7) and j=3 (k8,k9) ----
    #pragma unroll
    for (int r = 0; r < 3; ++r) load_row6(&sA[2][ty + r][tx4], Ai[r]);
    acc[0] = acc[1] = acc[2] = acc[3] = 0.f;
    do_pair(Ai, sA[1], ty, tx4, ker, 6, 7, acc);
    do_pair(Ai, sA[3], ty, tx4, ker, 8, 9, acc);
    {
        float4 o;
        float c0 = Ai[1][1], c1 = Ai[1][2], c2 = Ai[1][3], c3 = Ai[1][4];
        o.x = c0 * c0 * c0 - acc[0];
        o.y = c1 * c1 * c1 - acc[1];
        o.z = c2 * c2 * c2 - acc[2];
        o.w = c3 * c3 * c3 - acc[3];
        *(float4*)(out + ((size_t)2 * NIMG + n) * plane + (size_t)gy * WW + gx0) = o;
    }

    // ---- channel 3: bleed from j=2 (k10,k11) ----
    #pragma unroll
    for (int r = 0; r < 3; ++r) load_row6(&sA[3][ty + r][tx4], Ai[r]);
    acc[0] = acc[1] = acc[2] = acc[3] = 0.f;
    do_pair(Ai, sA[2], ty, tx4, ker, 10, 11, acc);
    {
        float4 o;
        float c0 = Ai[1][1], c1 = Ai[1][2], c2 = Ai[1][3], c3 = Ai[1][4];
        o.x = c0 * c0 * c0 - acc[0];
        o.y = c1 * c1 * c1 - acc[1];
        o.z = c2 * c2 * c2 - acc[2];
        o.w = c3 * c3 * c3 - acc[3];
        *(float4*)(out + ((size_t)3 * NIMG + n) * plane + (size_t)gy * WW + gx0) = o;
    }
}

extern "C" void kernel_launch(void* const* d_in, const int* in_sizes, int n_in,
                              void* d_out, int out_size, void* d_ws, size_t ws_size,
                              hipStream_t stream) {
    const float* src = (const float*)d_in[0];
    const float* ker = (const float*)d_in[1];
    float* out = (float*)d_out;

    dim3 grid(WW / TW, HH / TH, NIMG);   // (8, 32, 32) = 8192 blocks
    dim3 block(256);
    bleed_kernel<<<grid, block, 0, stream>>>(src, ker, out);
}